// Round 1
// baseline (1078.682 us; speedup 1.0000x reference)
//
#include <hip/hip_runtime.h>
#include <stdint.h>
#include <stddef.h>

// ---------------------------------------------------------------------------
// LorentzRankingLoss: exact re-implementation of the JAX reference.
// Pipeline: threshold-gather candidates per class -> per-class bitonic
// top-64 (exact (sort_key, idx) order) -> Lorentz distances (8192x128) ->
// threefry-driven top-8 negatives -> triplet loss reduction.
// PRNG: JAX threefry2x32, partitionable flavor (default since jax 0.4.30).
// Flip JAX_PARTITIONABLE to 0 if the harness runs the legacy PRNG.
// ---------------------------------------------------------------------------

#define JAX_PARTITIONABLE 1

static constexpr int C_CLASSES = 128;
static constexpr int NSAMP     = 64;
static constexpr int KMAX      = C_CLASSES * NSAMP;   // 8192
static constexpr int NNEG      = 8;
static constexpr int DIM       = 64;
static constexpr int SPATIAL   = 96 * 96 * 96;        // 884736
static constexpr int NTOT      = 2 * SPATIAL;         // 1769472
static constexpr int CAP       = 4096;                // per-class candidate cap
#define THRESH 0.125f                                  // pri gather threshold

// ---------------- threefry2x32 (matches jax._src.prng) ----------------
__host__ __device__ __forceinline__ void tf2x32(uint32_t k0, uint32_t k1,
                                                uint32_t x0, uint32_t x1,
                                                uint32_t& o0, uint32_t& o1) {
  uint32_t ks2 = k0 ^ k1 ^ 0x1BD11BDAu;
  x0 += k0; x1 += k1;
#define TF_R(r) { x0 += x1; x1 = (x1 << (r)) | (x1 >> (32 - (r))); x1 ^= x0; }
  TF_R(13) TF_R(15) TF_R(26) TF_R(6)
  x0 += k1;  x1 += ks2 + 1u;
  TF_R(17) TF_R(29) TF_R(16) TF_R(24)
  x0 += ks2; x1 += k0 + 2u;
  TF_R(13) TF_R(15) TF_R(26) TF_R(6)
  x0 += k0;  x1 += k1 + 3u;
  TF_R(17) TF_R(29) TF_R(16) TF_R(24)
  x0 += k1;  x1 += ks2 + 4u;
  TF_R(13) TF_R(15) TF_R(26) TF_R(6)
  x0 += ks2; x1 += k0 + 5u;
#undef TF_R
  o0 = x0; o1 = x1;
}

// random bits for linear index i of an array of `total` elements
__device__ __forceinline__ uint32_t jax_bits_at(uint32_t k0, uint32_t k1,
                                                uint32_t i, uint32_t half) {
  uint32_t o0, o1;
#if JAX_PARTITIONABLE
  (void)half;
  tf2x32(k0, k1, 0u, i, o0, o1);       // counter = 64-bit index (hi=0, lo=i)
  return o0 ^ o1;                      // 32-bit fold
#else
  if (i < half) { tf2x32(k0, k1, i, i + half, o0, o1); return o0; }
  tf2x32(k0, k1, i - half, i, o0, o1); return o1;
#endif
}

__device__ __forceinline__ float jax_uniform(uint32_t bits) {
  return __uint_as_float((bits >> 9) | 0x3F800000u) - 1.0f;
}

__device__ __forceinline__ uint32_t f32_orderable(float f) {
  uint32_t u = __float_as_uint(f);
  return (u & 0x80000000u) ? ~u : (u | 0x80000000u);
}

__device__ __forceinline__ unsigned long long umin64(unsigned long long a,
                                                     unsigned long long b) {
  return (a < b) ? a : b;
}

// ---------------- module-scope scratch (avoids relying on ws_size) -------
__device__ unsigned int       g_cand_cnt[C_CLASSES];
__device__ unsigned long long g_cand[C_CLASSES * CAP];   // (key_bits<<32)|idx
__device__ int                g_sampled_idx[KMAX];
__device__ int                g_valid[KMAX];
__device__ float              g_dpos[KMAX];
__device__ float              g_dists[KMAX * C_CLASSES];
__device__ double             g_loss_accum;
__device__ int                g_valid_total;

// ---------------- kernels ----------------
__global__ void k_init() {
  int t = threadIdx.x;
  if (t < C_CLASSES) g_cand_cnt[t] = 0u;
  if (t == 0) { g_loss_accum = 0.0; g_valid_total = 0; }
}

__global__ void k_gather(const int* __restrict__ labels,
                         uint32_t pk0, uint32_t pk1) {
  int i = blockIdx.x * blockDim.x + threadIdx.x;
  if (i >= NTOT) return;
  uint32_t bits = jax_bits_at(pk0, pk1, (uint32_t)i, (uint32_t)(NTOT / 2));
  float u = jax_uniform(bits);
  int lab = labels[i];
  if ((unsigned)lab >= (unsigned)C_CLASSES) return;   // defensive
  if (u < THRESH) {
    float skey = (float)lab * 2.0f + u;               // matches l*2.0 + pri
    unsigned pos = atomicAdd(&g_cand_cnt[lab], 1u);
    if (pos < (unsigned)CAP) {
      g_cand[lab * CAP + pos] =
          ((unsigned long long)__float_as_uint(skey) << 32) | (unsigned)i;
    }
  }
}

// one block per class: bitonic-sort candidates, emit 64 smallest in order
__global__ void k_select() {
  __shared__ unsigned long long sh[CAP];
  const int c   = blockIdx.x;
  const int tid = threadIdx.x;
  unsigned n = g_cand_cnt[c];
  if (n > (unsigned)CAP) n = CAP;
  for (int i = tid; i < CAP; i += 256)
    sh[i] = (i < (int)n) ? g_cand[c * CAP + i] : 0xFFFFFFFFFFFFFFFFULL;
  __syncthreads();
  for (unsigned k = 2; k <= (unsigned)CAP; k <<= 1) {
    for (unsigned j = k >> 1; j > 0; j >>= 1) {
      for (unsigned i = tid; i < (unsigned)CAP; i += 256) {
        unsigned ixj = i ^ j;
        if (ixj > i) {
          unsigned long long a = sh[i], b = sh[ixj];
          bool up = ((i & k) == 0);
          bool sw = up ? (a > b) : (a < b);
          if (sw) { sh[i] = b; sh[ixj] = a; }
        }
      }
      __syncthreads();
    }
  }
  int nv = (int)((n < (unsigned)NSAMP) ? n : (unsigned)NSAMP);
  if (tid < NSAMP) {
    int slot = c * NSAMP + tid;
    bool v = tid < nv;
    g_sampled_idx[slot] = v ? (int)(unsigned)(sh[tid] & 0xFFFFFFFFull) : 0;
    g_valid[slot] = v ? 1 : 0;
  }
  if (tid == 0) atomicAdd(&g_valid_total, nv);
}

// one block per class: 64 anchors x 128 classes Lorentz distances
__global__ void k_dists(const float* __restrict__ voxel,
                        const float* __restrict__ lemb) {
  __shared__ float Lsh[C_CLASSES][DIM + 1];
  __shared__ float Ash[NSAMP][DIM + 1];
  __shared__ float tL[C_CLASSES];
  __shared__ float tA[NSAMP];
  const int c0  = blockIdx.x;
  const int tid = threadIdx.x;

  for (int i = tid; i < C_CLASSES * DIM; i += 256) {
    int c = i >> 6, d = i & 63;
    Lsh[c][d] = lemb[i];
  }
  for (int i = tid; i < NSAMP * DIM; i += 256) {
    int r = i >> 6, d = i & 63;
    int n = g_sampled_idx[c0 * NSAMP + r];
    int b = n / SPATIAL;
    int s = n - b * SPATIAL;
    Ash[r][d] = voxel[(size_t)(b * DIM + d) * (size_t)SPATIAL + (size_t)s];
  }
  __syncthreads();
  if (tid < C_CLASSES) {
    float sum = 0.0f;
    for (int d = 0; d < DIM; ++d) { float v = Lsh[tid][d]; sum += v * v; }
    tL[tid] = sqrtf(1.0f + sum);
  } else if (tid < C_CLASSES + NSAMP) {
    int r = tid - C_CLASSES;
    float sum = 0.0f;
    for (int d = 0; d < DIM; ++d) { float v = Ash[r][d]; sum += v * v; }
    tA[r] = sqrtf(1.0f + sum);
  }
  __syncthreads();
  for (int p = tid; p < NSAMP * C_CLASSES; p += 256) {
    int r = p >> 7, c = p & 127;
    float sum = 0.0f;
#pragma unroll
    for (int d = 0; d < DIM; ++d) sum = fmaf(Ash[r][d], Lsh[c][d], sum);
    float inner = sum - tA[r] * tL[c];
    float z = fmaxf(-inner, 1.0000001192092896f);     // clip(-inner, 1+1e-7)
    float dist = acoshf(z);
    int k = c0 * NSAMP + r;
    g_dists[k * C_CLASSES + c] = dist;
    if (c == c0) g_dpos[k] = dist;
  }
}

// thread per anchor row: top-8 negatives (value desc, idx asc) + triplet sum
__global__ void k_loss(uint32_t nk0, uint32_t nk1) {
  const int tid = threadIdx.x;
  const int k = blockIdx.x * blockDim.x + tid;
  float contrib = 0.0f;
  if (k < KMAX) {
    const int cls = k >> 6;
    // 8 slots, packed (orderable(value)<<32)|(127-c); worst = numeric min
    unsigned long long s0 = 0, s1 = 1, s2 = 2, s3 = 3,
                       s4 = 4, s5 = 5, s6 = 6, s7 = 7;
    for (int c = 0; c < C_CLASSES; ++c) {
      uint32_t m = (uint32_t)(k * C_CLASSES + c);
      uint32_t bits = jax_bits_at(nk0, nk1, m, (uint32_t)(KMAX * C_CLASSES / 2));
      float v = (c == cls) ? -1.0f : jax_uniform(bits);
      unsigned long long key =
          ((unsigned long long)f32_orderable(v) << 32) | (unsigned)(127 - c);
      unsigned long long w = umin64(umin64(umin64(s0, s1), umin64(s2, s3)),
                                    umin64(umin64(s4, s5), umin64(s6, s7)));
      if (key > w) {
        s0 = (s0 == w) ? key : s0;  s1 = (s1 == w) ? key : s1;
        s2 = (s2 == w) ? key : s2;  s3 = (s3 == w) ? key : s3;
        s4 = (s4 == w) ? key : s4;  s5 = (s5 == w) ? key : s5;
        s6 = (s6 == w) ? key : s6;  s7 = (s7 == w) ? key : s7;
      }
    }
    float dp = g_dpos[k];
    float ssum = 0.0f;
#define TAKE(S) { int c_ = 127 - (int)((S) & 0xFFFFFFFFull); \
                  float dn_ = g_dists[k * C_CLASSES + c_]; \
                  ssum += fmaxf(0.1f + dp - dn_, 0.0f); }
    TAKE(s0) TAKE(s1) TAKE(s2) TAKE(s3) TAKE(s4) TAKE(s5) TAKE(s6) TAKE(s7)
#undef TAKE
    contrib = g_valid[k] ? ssum : 0.0f;
  }
  __shared__ double red[256];
  red[tid] = (double)contrib;
  __syncthreads();
  for (int off = 128; off > 0; off >>= 1) {
    if (tid < off) red[tid] += red[tid + off];
    __syncthreads();
  }
  if (tid == 0) atomicAdd(&g_loss_accum, red[0]);
}

__global__ void k_final(float* __restrict__ out) {
  double denom = (double)g_valid_total * (double)NNEG;
  if (denom < 1.0) denom = 1.0;
  out[0] = (float)(g_loss_accum / denom);
}

// ---------------- host ----------------
extern "C" void kernel_launch(void* const* d_in, const int* in_sizes, int n_in,
                              void* d_out, int out_size, void* d_ws, size_t ws_size,
                              hipStream_t stream) {
  (void)in_sizes; (void)n_in; (void)out_size; (void)d_ws; (void)ws_size;
  const float* voxel  = (const float*)d_in[0];
  const int*   labels = (const int*)d_in[1];
  const float* lemb   = (const float*)d_in[2];
  float*       out    = (float*)d_out;

  // derive k_pri / k_neg from key(42) on host (pure CPU, graph-capture safe)
  uint32_t pk0, pk1, nk0, nk1;
#if JAX_PARTITIONABLE
  tf2x32(0u, 42u, 0u, 0u, pk0, pk1);   // split foldlike: key i = block(0, i)
  tf2x32(0u, 42u, 0u, 1u, nk0, nk1);
#else
  uint32_t a0, a1, b0, b1;
  tf2x32(0u, 42u, 0u, 2u, a0, b0);     // original split: pairs (0,2),(1,3)
  tf2x32(0u, 42u, 1u, 3u, a1, b1);
  pk0 = a0; pk1 = a1; nk0 = b0; nk1 = b1;
#endif

  k_init<<<1, 256, 0, stream>>>();
  k_gather<<<NTOT / 256, 256, 0, stream>>>(labels, pk0, pk1);
  k_select<<<C_CLASSES, 256, 0, stream>>>();
  k_dists<<<C_CLASSES, 256, 0, stream>>>(voxel, lemb);
  k_loss<<<KMAX / 256, 256, 0, stream>>>(nk0, nk1);
  k_final<<<1, 1, 0, stream>>>(out);
}

// Round 3
// 585.274 us; speedup vs baseline: 1.8430x; 1.8430x over previous
//
#include <hip/hip_runtime.h>
#include <stdint.h>
#include <stddef.h>

// ---------------------------------------------------------------------------
// LorentzRankingLoss — exact reimplementation of the JAX reference.
// R2 (resubmitted R3 after GPU timeout): sharded gather atomics (16x),
// THRESH 0.125->0.02 (sort 4096->512), fused per-class kernel
// (select + anchor gather + neg pick + 9 dots + loss).
// PRNG: JAX threefry2x32, partitionable flavor (verified bit-exact in R1).
// ---------------------------------------------------------------------------

#define JAX_PARTITIONABLE 1

static constexpr int C_CLASSES = 128;
static constexpr int NSAMP     = 64;
static constexpr int KMAX      = C_CLASSES * NSAMP;   // 8192
static constexpr int NNEG      = 8;
static constexpr int DIM       = 64;
static constexpr int SPATIAL   = 96 * 96 * 96;        // 884736
static constexpr int NTOT      = 2 * SPATIAL;         // 1769472
static constexpr int SH        = 16;                  // atomic shards per class
static constexpr int SLOT      = 64;                  // slots per (class,shard)
static constexpr int CSORT     = 512;                 // per-class sort size
#define THRESH 0.02f   // 64th order stat ~0.0046; mean 276/class; P(<64)~1e-36

// ---------------- threefry2x32 (matches jax._src.prng) ----------------
__host__ __device__ __forceinline__ void tf2x32(uint32_t k0, uint32_t k1,
                                                uint32_t x0, uint32_t x1,
                                                uint32_t& o0, uint32_t& o1) {
  uint32_t ks2 = k0 ^ k1 ^ 0x1BD11BDAu;
  x0 += k0; x1 += k1;
#define TF_R(r) { x0 += x1; x1 = (x1 << (r)) | (x1 >> (32 - (r))); x1 ^= x0; }
  TF_R(13) TF_R(15) TF_R(26) TF_R(6)
  x0 += k1;  x1 += ks2 + 1u;
  TF_R(17) TF_R(29) TF_R(16) TF_R(24)
  x0 += ks2; x1 += k0 + 2u;
  TF_R(13) TF_R(15) TF_R(26) TF_R(6)
  x0 += k0;  x1 += k1 + 3u;
  TF_R(17) TF_R(29) TF_R(16) TF_R(24)
  x0 += k1;  x1 += ks2 + 4u;
  TF_R(13) TF_R(15) TF_R(26) TF_R(6)
  x0 += ks2; x1 += k0 + 5u;
#undef TF_R
  o0 = x0; o1 = x1;
}

__device__ __forceinline__ uint32_t jax_bits_at(uint32_t k0, uint32_t k1,
                                                uint32_t i, uint32_t half) {
  uint32_t o0, o1;
#if JAX_PARTITIONABLE
  (void)half;
  tf2x32(k0, k1, 0u, i, o0, o1);
  return o0 ^ o1;
#else
  if (i < half) { tf2x32(k0, k1, i, i + half, o0, o1); return o0; }
  tf2x32(k0, k1, i - half, i, o0, o1); return o1;
#endif
}

__device__ __forceinline__ float jax_uniform(uint32_t bits) {
  return __uint_as_float((bits >> 9) | 0x3F800000u) - 1.0f;
}

__device__ __forceinline__ uint32_t f32_orderable(float f) {
  uint32_t u = __float_as_uint(f);
  return (u & 0x80000000u) ? ~u : (u | 0x80000000u);
}

__device__ __forceinline__ unsigned long long umin64(unsigned long long a,
                                                     unsigned long long b) {
  return (a < b) ? a : b;
}

// ---------------- module-scope scratch ----------------
__device__ unsigned int       g_cnt[C_CLASSES * SH];
__device__ unsigned long long g_cand[C_CLASSES * SH * SLOT];  // (key<<32)|idx
__device__ double             g_loss_accum;
__device__ int                g_valid_total;

// ---------------- kernels ----------------
__global__ void k_init() {
  int t = threadIdx.x;
  for (int i = t; i < C_CLASSES * SH; i += 256) g_cnt[i] = 0u;
  if (t == 0) { g_loss_accum = 0.0; g_valid_total = 0; }
}

__global__ void k_gather(const int* __restrict__ labels,
                         uint32_t pk0, uint32_t pk1) {
  int i = blockIdx.x * blockDim.x + threadIdx.x;
  if (i >= NTOT) return;
  uint32_t bits = jax_bits_at(pk0, pk1, (uint32_t)i, (uint32_t)(NTOT / 2));
  float u = jax_uniform(bits);
  int lab = labels[i];
  if ((unsigned)lab >= (unsigned)C_CLASSES) return;   // defensive
  if (u < THRESH) {
    float skey = (float)lab * 2.0f + u;               // matches l*2.0 + pri
    int shard = i & (SH - 1);
    unsigned cell = (unsigned)(lab * SH + shard);
    unsigned pos = atomicAdd(&g_cnt[cell], 1u);
    if (pos < (unsigned)SLOT) {
      g_cand[cell * SLOT + pos] =
          ((unsigned long long)__float_as_uint(skey) << 32) | (unsigned)i;
    }
  }
}

// one block per class: compact shards -> bitonic-512 -> top-64 anchors ->
// neg pick (threefry) -> 9 Lorentz dists per row -> triplet partial sum
__global__ void __launch_bounds__(256)
k_class(const float* __restrict__ voxel, const float* __restrict__ lemb,
        uint32_t nk0, uint32_t nk1) {
  __shared__ unsigned long long sh[CSORT];
  __shared__ float Lsh[C_CLASSES][DIM + 1];
  __shared__ float Ash[NSAMP][DIM + 1];
  __shared__ float tL[C_CLASSES];
  __shared__ float tA[NSAMP];
  __shared__ int   sidx[NSAMP];
  __shared__ int   s_nv;
  __shared__ unsigned s_pf[SH];
  __shared__ unsigned s_ct[SH];
  __shared__ double red[256];

  const int c0  = blockIdx.x;
  const int tid = threadIdx.x;

  // init sort buffer to +INF keys; stream in label embeddings meanwhile
  for (int i = tid; i < CSORT; i += 256) sh[i] = 0xFFFFFFFFFFFFFFFFULL;
  for (int i = tid; i < C_CLASSES * DIM; i += 256)
    Lsh[i >> 6][i & 63] = lemb[i];
  __syncthreads();

  // prefix-sum shard counts (clamped) — tiny, thread 0
  if (tid == 0) {
    unsigned acc = 0;
    for (int s = 0; s < SH; ++s) {
      unsigned c = g_cnt[c0 * SH + s];
      if (c > (unsigned)SLOT) c = SLOT;
      if (acc + c > (unsigned)CSORT) c = CSORT - acc;   // impossible; defensive
      s_pf[s] = acc; s_ct[s] = c; acc += c;
    }
    s_nv = (int)((acc < (unsigned)NSAMP) ? acc : (unsigned)NSAMP);
  }
  __syncthreads();

  // compact candidates
  for (int s = 0; s < SH; ++s) {
    unsigned base = s_pf[s], ct = s_ct[s];
    for (unsigned j = tid; j < ct; j += 256)
      sh[base + j] = g_cand[(c0 * SH + s) * SLOT + j];
  }
  __syncthreads();

  // bitonic sort 512 (ascending (key,idx)) — exact argsort-stable order
  for (unsigned k = 2; k <= (unsigned)CSORT; k <<= 1) {
    for (unsigned j = k >> 1; j > 0; j >>= 1) {
      for (unsigned i = tid; i < (unsigned)CSORT; i += 256) {
        unsigned ixj = i ^ j;
        if (ixj > i) {
          unsigned long long a = sh[i], b = sh[ixj];
          bool up = ((i & k) == 0);
          bool sw = up ? (a > b) : (a < b);
          if (sw) { sh[i] = b; sh[ixj] = a; }
        }
      }
      __syncthreads();
    }
  }

  if (tid < NSAMP) {
    bool v = tid < s_nv;
    sidx[tid] = v ? (int)(unsigned)(sh[tid] & 0xFFFFFFFFull) : 0;
  }
  if (tid == 0) atomicAdd(&g_valid_total, s_nv);
  __syncthreads();

  // gather anchors [64][64] (scattered HBM reads)
  for (int i = tid; i < NSAMP * DIM; i += 256) {
    int r = i >> 6, d = i & 63;
    int n = sidx[r];
    int b = n / SPATIAL;
    int s = n - b * SPATIAL;
    Ash[r][d] = voxel[(size_t)(b * DIM + d) * (size_t)SPATIAL + (size_t)s];
  }
  __syncthreads();

  // Lorentz time components
  if (tid < C_CLASSES) {
    float sum = 0.0f;
#pragma unroll
    for (int d = 0; d < DIM; ++d) { float v = Lsh[tid][d]; sum += v * v; }
    tL[tid] = sqrtf(1.0f + sum);
  } else if (tid < C_CLASSES + NSAMP) {
    int r = tid - C_CLASSES;
    float sum = 0.0f;
#pragma unroll
    for (int d = 0; d < DIM; ++d) { float v = Ash[r][d]; sum += v * v; }
    tA[r] = sqrtf(1.0f + sum);
  }
  __syncthreads();

  // per-row: top-8 negatives (value desc, idx asc) then 9 dists + triplet
  float contrib = 0.0f;
  if (tid < NSAMP) {
    const int r = tid;
    const int k = c0 * NSAMP + r;
    unsigned long long s0 = 0, s1 = 1, s2 = 2, s3 = 3,
                       s4 = 4, s5 = 5, s6 = 6, s7 = 7;
    for (int c = 0; c < C_CLASSES; ++c) {
      uint32_t m = (uint32_t)(k * C_CLASSES + c);
      uint32_t bits = jax_bits_at(nk0, nk1, m, (uint32_t)(KMAX * C_CLASSES / 2));
      float v = (c == c0) ? -1.0f : jax_uniform(bits);
      unsigned long long key =
          ((unsigned long long)f32_orderable(v) << 32) | (unsigned)(127 - c);
      unsigned long long w = umin64(umin64(umin64(s0, s1), umin64(s2, s3)),
                                    umin64(umin64(s4, s5), umin64(s6, s7)));
      if (key > w) {
        s0 = (s0 == w) ? key : s0;  s1 = (s1 == w) ? key : s1;
        s2 = (s2 == w) ? key : s2;  s3 = (s3 == w) ? key : s3;
        s4 = (s4 == w) ? key : s4;  s5 = (s5 == w) ? key : s5;
        s6 = (s6 == w) ? key : s6;  s7 = (s7 == w) ? key : s7;
      }
    }
    // d_pos
    float dp;
    {
      float sum = 0.0f;
#pragma unroll
      for (int d = 0; d < DIM; ++d) sum = fmaf(Ash[r][d], Lsh[c0][d], sum);
      float inner = sum - tA[r] * tL[c0];
      dp = acoshf(fmaxf(-inner, 1.0000001192092896f));
    }
    float ssum = 0.0f;
#define TAKE(S) { int c_ = 127 - (int)((S) & 0xFFFFFFFFull); \
                  float sum_ = 0.0f; \
                  _Pragma("unroll") \
                  for (int d = 0; d < DIM; ++d) \
                    sum_ = fmaf(Ash[r][d], Lsh[c_][d], sum_); \
                  float inner_ = sum_ - tA[r] * tL[c_]; \
                  float dn_ = acoshf(fmaxf(-inner_, 1.0000001192092896f)); \
                  ssum += fmaxf(0.1f + dp - dn_, 0.0f); }
    TAKE(s0) TAKE(s1) TAKE(s2) TAKE(s3) TAKE(s4) TAKE(s5) TAKE(s6) TAKE(s7)
#undef TAKE
    contrib = (r < s_nv) ? ssum : 0.0f;
  }

  red[tid] = (double)contrib;
  __syncthreads();
  for (int off = 128; off > 0; off >>= 1) {
    if (tid < off) red[tid] += red[tid + off];
    __syncthreads();
  }
  if (tid == 0) atomicAdd(&g_loss_accum, red[0]);
}

__global__ void k_final(float* __restrict__ out) {
  double denom = (double)g_valid_total * (double)NNEG;
  if (denom < 1.0) denom = 1.0;
  out[0] = (float)(g_loss_accum / denom);
}

// ---------------- host ----------------
extern "C" void kernel_launch(void* const* d_in, const int* in_sizes, int n_in,
                              void* d_out, int out_size, void* d_ws, size_t ws_size,
                              hipStream_t stream) {
  (void)in_sizes; (void)n_in; (void)out_size; (void)d_ws; (void)ws_size;
  const float* voxel  = (const float*)d_in[0];
  const int*   labels = (const int*)d_in[1];
  const float* lemb   = (const float*)d_in[2];
  float*       out    = (float*)d_out;

  uint32_t pk0, pk1, nk0, nk1;
#if JAX_PARTITIONABLE
  tf2x32(0u, 42u, 0u, 0u, pk0, pk1);
  tf2x32(0u, 42u, 0u, 1u, nk0, nk1);
#else
  uint32_t a0, a1, b0, b1;
  tf2x32(0u, 42u, 0u, 2u, a0, b0);
  tf2x32(0u, 42u, 1u, 3u, a1, b1);
  pk0 = a0; pk1 = a1; nk0 = b0; nk1 = b1;
#endif

  k_init<<<1, 256, 0, stream>>>();
  k_gather<<<NTOT / 256, 256, 0, stream>>>(labels, pk0, pk1);
  k_class<<<C_CLASSES, 256, 0, stream>>>(voxel, lemb, nk0, nk1);
  k_final<<<1, 1, 0, stream>>>(out);
}

// Round 5
// 579.838 us; speedup vs baseline: 1.8603x; 1.0094x over previous
//
#include <hip/hip_runtime.h>
#include <stdint.h>
#include <stddef.h>

// ---------------------------------------------------------------------------
// LorentzRankingLoss — exact reimplementation of the JAX reference.
// R4 (resubmitted R5 after GPU timeout): gather atomics sharded 64x with
// 64B-padded counters (kills TCC chain + line serialization; R1 calibration:
// ~202ns per same-address atomic), parallel shard-count scan in k_class.
// Pipeline otherwise as R2 (verified bit-exact twice: absmax = 0.0).
// PRNG: JAX threefry2x32, partitionable flavor.
// ---------------------------------------------------------------------------

#define JAX_PARTITIONABLE 1

static constexpr int C_CLASSES = 128;
static constexpr int NSAMP     = 64;
static constexpr int KMAX      = C_CLASSES * NSAMP;   // 8192
static constexpr int NNEG      = 8;
static constexpr int DIM       = 64;
static constexpr int SPATIAL   = 96 * 96 * 96;        // 884736
static constexpr int NTOT      = 2 * SPATIAL;         // 1769472
static constexpr int SH        = 64;                  // atomic shards per class
static constexpr int SLOT      = 32;                  // slots per (class,shard)
static constexpr int CSORT     = 512;                 // per-class sort size
static constexpr int CNT_PAD   = 16;                  // 16 uints = 64B line
#define THRESH 0.02f   // 64th order stat ~0.0046; mean 276/class; P(<64)~1e-36

// ---------------- threefry2x32 (matches jax._src.prng) ----------------
__host__ __device__ __forceinline__ void tf2x32(uint32_t k0, uint32_t k1,
                                                uint32_t x0, uint32_t x1,
                                                uint32_t& o0, uint32_t& o1) {
  uint32_t ks2 = k0 ^ k1 ^ 0x1BD11BDAu;
  x0 += k0; x1 += k1;
#define TF_R(r) { x0 += x1; x1 = (x1 << (r)) | (x1 >> (32 - (r))); x1 ^= x0; }
  TF_R(13) TF_R(15) TF_R(26) TF_R(6)
  x0 += k1;  x1 += ks2 + 1u;
  TF_R(17) TF_R(29) TF_R(16) TF_R(24)
  x0 += ks2; x1 += k0 + 2u;
  TF_R(13) TF_R(15) TF_R(26) TF_R(6)
  x0 += k0;  x1 += k1 + 3u;
  TF_R(17) TF_R(29) TF_R(16) TF_R(24)
  x0 += k1;  x1 += ks2 + 4u;
  TF_R(13) TF_R(15) TF_R(26) TF_R(6)
  x0 += ks2; x1 += k0 + 5u;
#undef TF_R
  o0 = x0; o1 = x1;
}

__device__ __forceinline__ uint32_t jax_bits_at(uint32_t k0, uint32_t k1,
                                                uint32_t i, uint32_t half) {
  uint32_t o0, o1;
#if JAX_PARTITIONABLE
  (void)half;
  tf2x32(k0, k1, 0u, i, o0, o1);
  return o0 ^ o1;
#else
  if (i < half) { tf2x32(k0, k1, i, i + half, o0, o1); return o0; }
  tf2x32(k0, k1, i - half, i, o0, o1); return o1;
#endif
}

__device__ __forceinline__ float jax_uniform(uint32_t bits) {
  return __uint_as_float((bits >> 9) | 0x3F800000u) - 1.0f;
}

__device__ __forceinline__ uint32_t f32_orderable(float f) {
  uint32_t u = __float_as_uint(f);
  return (u & 0x80000000u) ? ~u : (u | 0x80000000u);
}

__device__ __forceinline__ unsigned long long umin64(unsigned long long a,
                                                     unsigned long long b) {
  return (a < b) ? a : b;
}

// ---------------- module-scope scratch ----------------
__device__ unsigned int       g_cnt[C_CLASSES * SH * CNT_PAD];  // 64B/counter
__device__ unsigned long long g_cand[C_CLASSES * SH * SLOT];    // (key<<32)|idx
__device__ double             g_loss_accum;
__device__ int                g_valid_total;

// ---------------- kernels ----------------
__global__ void k_init() {
  int i = blockIdx.x * blockDim.x + threadIdx.x;
  if (i < C_CLASSES * SH) g_cnt[i * CNT_PAD] = 0u;
  if (i == 0) { g_loss_accum = 0.0; g_valid_total = 0; }
}

__global__ void k_gather(const int* __restrict__ labels,
                         uint32_t pk0, uint32_t pk1) {
  int i = blockIdx.x * blockDim.x + threadIdx.x;
  if (i >= NTOT) return;
  uint32_t bits = jax_bits_at(pk0, pk1, (uint32_t)i, (uint32_t)(NTOT / 2));
  float u = jax_uniform(bits);
  int lab = labels[i];
  if ((unsigned)lab >= (unsigned)C_CLASSES) return;   // defensive
  if (u < THRESH) {
    float skey = (float)lab * 2.0f + u;               // matches l*2.0 + pri
    int shard = i & (SH - 1);
    unsigned cell = (unsigned)(lab * SH + shard);
    unsigned pos = atomicAdd(&g_cnt[cell * CNT_PAD], 1u);
    if (pos < (unsigned)SLOT) {
      g_cand[cell * SLOT + pos] =
          ((unsigned long long)__float_as_uint(skey) << 32) | (unsigned)i;
    }
  }
}

// one block per class: compact shards -> bitonic-512 -> top-64 anchors ->
// neg pick (threefry) -> 9 Lorentz dists per row -> triplet partial sum
__global__ void __launch_bounds__(256)
k_class(const float* __restrict__ voxel, const float* __restrict__ lemb,
        uint32_t nk0, uint32_t nk1) {
  __shared__ unsigned long long sh[CSORT];
  __shared__ float Lsh[C_CLASSES][DIM + 1];
  __shared__ float Ash[NSAMP][DIM + 1];
  __shared__ float tL[C_CLASSES];
  __shared__ float tA[NSAMP];
  __shared__ int   sidx[NSAMP];
  __shared__ int   s_nv;
  __shared__ unsigned s_pf[SH];   // exclusive prefix of clamped counts
  __shared__ unsigned s_ct[SH];
  __shared__ unsigned s_scan[SH];
  __shared__ double red[256];

  const int c0  = blockIdx.x;
  const int tid = threadIdx.x;

  // init sort buffer to +INF keys; stream in label embeddings meanwhile
  for (int i = tid; i < CSORT; i += 256) sh[i] = 0xFFFFFFFFFFFFFFFFULL;
  for (int i = tid; i < C_CLASSES * DIM; i += 256)
    Lsh[i >> 6][i & 63] = lemb[i];

  // load + clamp shard counts (64 parallel loads)
  if (tid < SH) {
    unsigned c = g_cnt[(c0 * SH + tid) * CNT_PAD];
    if (c > (unsigned)SLOT) c = SLOT;
    s_ct[tid] = c;
    s_scan[tid] = c;
  }
  __syncthreads();

  // Hillis–Steele inclusive scan over 64 counts
#pragma unroll
  for (int off = 1; off < SH; off <<= 1) {
    unsigned v = 0;
    if (tid < SH && tid >= off) v = s_scan[tid - off];
    __syncthreads();
    if (tid < SH) s_scan[tid] += v;
    __syncthreads();
  }
  if (tid < SH) s_pf[tid] = s_scan[tid] - s_ct[tid];   // exclusive
  if (tid == 0) {
    unsigned total = s_scan[SH - 1];
    if (total > (unsigned)CSORT) total = CSORT;        // impossible; defensive
    s_nv = (int)((total < (unsigned)NSAMP) ? total : (unsigned)NSAMP);
  }
  __syncthreads();

  // compact candidates (shard t copies its own entries)
  if (tid < SH) {
    unsigned base = s_pf[tid], ct = s_ct[tid];
    if (base > (unsigned)CSORT) base = CSORT;
    if (base + ct > (unsigned)CSORT) ct = CSORT - base;
    for (unsigned j = 0; j < ct; ++j)
      sh[base + j] = g_cand[(c0 * SH + tid) * SLOT + j];
  }
  __syncthreads();

  // bitonic sort 512 (ascending (key,idx)) — exact argsort-stable order
  for (unsigned k = 2; k <= (unsigned)CSORT; k <<= 1) {
    for (unsigned j = k >> 1; j > 0; j >>= 1) {
      for (unsigned i = tid; i < (unsigned)CSORT; i += 256) {
        unsigned ixj = i ^ j;
        if (ixj > i) {
          unsigned long long a = sh[i], b = sh[ixj];
          bool up = ((i & k) == 0);
          bool sw = up ? (a > b) : (a < b);
          if (sw) { sh[i] = b; sh[ixj] = a; }
        }
      }
      __syncthreads();
    }
  }

  if (tid < NSAMP) {
    bool v = tid < s_nv;
    sidx[tid] = v ? (int)(unsigned)(sh[tid] & 0xFFFFFFFFull) : 0;
  }
  if (tid == 0) atomicAdd(&g_valid_total, s_nv);
  __syncthreads();

  // gather anchors [64][64] (scattered HBM reads)
  for (int i = tid; i < NSAMP * DIM; i += 256) {
    int r = i >> 6, d = i & 63;
    int n = sidx[r];
    int b = n / SPATIAL;
    int s = n - b * SPATIAL;
    Ash[r][d] = voxel[(size_t)(b * DIM + d) * (size_t)SPATIAL + (size_t)s];
  }
  __syncthreads();

  // Lorentz time components
  if (tid < C_CLASSES) {
    float sum = 0.0f;
#pragma unroll
    for (int d = 0; d < DIM; ++d) { float v = Lsh[tid][d]; sum += v * v; }
    tL[tid] = sqrtf(1.0f + sum);
  } else if (tid < C_CLASSES + NSAMP) {
    int r = tid - C_CLASSES;
    float sum = 0.0f;
#pragma unroll
    for (int d = 0; d < DIM; ++d) { float v = Ash[r][d]; sum += v * v; }
    tA[r] = sqrtf(1.0f + sum);
  }
  __syncthreads();

  // per-row: top-8 negatives (value desc, idx asc) then 9 dists + triplet
  float contrib = 0.0f;
  if (tid < NSAMP) {
    const int r = tid;
    const int k = c0 * NSAMP + r;
    unsigned long long s0 = 0, s1 = 1, s2 = 2, s3 = 3,
                       s4 = 4, s5 = 5, s6 = 6, s7 = 7;
    for (int c = 0; c < C_CLASSES; ++c) {
      uint32_t m = (uint32_t)(k * C_CLASSES + c);
      uint32_t bits = jax_bits_at(nk0, nk1, m, (uint32_t)(KMAX * C_CLASSES / 2));
      float v = (c == c0) ? -1.0f : jax_uniform(bits);
      unsigned long long key =
          ((unsigned long long)f32_orderable(v) << 32) | (unsigned)(127 - c);
      unsigned long long w = umin64(umin64(umin64(s0, s1), umin64(s2, s3)),
                                    umin64(umin64(s4, s5), umin64(s6, s7)));
      if (key > w) {
        s0 = (s0 == w) ? key : s0;  s1 = (s1 == w) ? key : s1;
        s2 = (s2 == w) ? key : s2;  s3 = (s3 == w) ? key : s3;
        s4 = (s4 == w) ? key : s4;  s5 = (s5 == w) ? key : s5;
        s6 = (s6 == w) ? key : s6;  s7 = (s7 == w) ? key : s7;
      }
    }
    // d_pos
    float dp;
    {
      float sum = 0.0f;
#pragma unroll
      for (int d = 0; d < DIM; ++d) sum = fmaf(Ash[r][d], Lsh[c0][d], sum);
      float inner = sum - tA[r] * tL[c0];
      dp = acoshf(fmaxf(-inner, 1.0000001192092896f));
    }
    float ssum = 0.0f;
#define TAKE(S) { int c_ = 127 - (int)((S) & 0xFFFFFFFFull); \
                  float sum_ = 0.0f; \
                  _Pragma("unroll") \
                  for (int d = 0; d < DIM; ++d) \
                    sum_ = fmaf(Ash[r][d], Lsh[c_][d], sum_); \
                  float inner_ = sum_ - tA[r] * tL[c_]; \
                  float dn_ = acoshf(fmaxf(-inner_, 1.0000001192092896f)); \
                  ssum += fmaxf(0.1f + dp - dn_, 0.0f); }
    TAKE(s0) TAKE(s1) TAKE(s2) TAKE(s3) TAKE(s4) TAKE(s5) TAKE(s6) TAKE(s7)
#undef TAKE
    contrib = (r < s_nv) ? ssum : 0.0f;
  }

  red[tid] = (double)contrib;
  __syncthreads();
  for (int off = 128; off > 0; off >>= 1) {
    if (tid < off) red[tid] += red[tid + off];
    __syncthreads();
  }
  if (tid == 0) atomicAdd(&g_loss_accum, red[0]);
}

__global__ void k_final(float* __restrict__ out) {
  double denom = (double)g_valid_total * (double)NNEG;
  if (denom < 1.0) denom = 1.0;
  out[0] = (float)(g_loss_accum / denom);
}

// ---------------- host ----------------
extern "C" void kernel_launch(void* const* d_in, const int* in_sizes, int n_in,
                              void* d_out, int out_size, void* d_ws, size_t ws_size,
                              hipStream_t stream) {
  (void)in_sizes; (void)n_in; (void)out_size; (void)d_ws; (void)ws_size;
  const float* voxel  = (const float*)d_in[0];
  const int*   labels = (const int*)d_in[1];
  const float* lemb   = (const float*)d_in[2];
  float*       out    = (float*)d_out;

  uint32_t pk0, pk1, nk0, nk1;
#if JAX_PARTITIONABLE
  tf2x32(0u, 42u, 0u, 0u, pk0, pk1);
  tf2x32(0u, 42u, 0u, 1u, nk0, nk1);
#else
  uint32_t a0, a1, b0, b1;
  tf2x32(0u, 42u, 0u, 2u, a0, b0);
  tf2x32(0u, 42u, 1u, 3u, a1, b1);
  pk0 = a0; pk1 = a1; nk0 = b0; nk1 = b1;
#endif

  k_init<<<(C_CLASSES * SH + 255) / 256, 256, 0, stream>>>();
  k_gather<<<NTOT / 256, 256, 0, stream>>>(labels, pk0, pk1);
  k_class<<<C_CLASSES, 256, 0, stream>>>(voxel, lemb, nk0, nk1);
  k_final<<<1, 1, 0, stream>>>(out);
}